// Round 15
// baseline (250.274 us; speedup 1.0000x reference)
//
#include <hip/hip_runtime.h>

#define THREADS 256
#define CAP 128

typedef float floatx4 __attribute__((ext_vector_type(4)));

static __device__ __forceinline__ unsigned short f2b(float x) {
    unsigned int u = __float_as_uint(x);
    u += 0x7FFFu + ((u >> 16) & 1u);          // round-to-nearest-even
    return (unsigned short)(u >> 16);
}
static __device__ __forceinline__ float b2f(unsigned short h) {
    return __uint_as_float(((unsigned int)h) << 16);
}

// ---------------- boundary-cost probe: no-op dispatch ----------------
__global__ void probe_kernel(int* __restrict__ sink) {
    if (blockIdx.x == 0 && threadIdx.x == 0) *sink = 1;
}

// ---------------- phase 0: zero row counters ----------------

__global__ void zero_kernel(int* __restrict__ p, int n) {
    int i = blockIdx.x * blockDim.x + threadIdx.x;
    if (i < n) p[i] = 0;
}

// ---------------- phase 1 (merged): ELL scatter  ||  gemm0 (fp32 in, bf16 out) ----------------

__global__ void build_and_gemm0_kernel(const int* __restrict__ row, const int* __restrict__ col,
                                       const float* __restrict__ val, int* __restrict__ nxt,
                                       int* __restrict__ ell_c, float* __restrict__ ell_v, int E,
                                       const float* __restrict__ X, const float* __restrict__ W0,
                                       unsigned short* __restrict__ Y, int n, int K, int gridE) {
    if ((int)blockIdx.x < gridE) {
        int e = blockIdx.x * THREADS + threadIdx.x;
        if (e < E) {
            int r = row[e];
            int p = atomicAdd(&nxt[r], 1);
            if (p < CAP) {
                ell_c[r * CAP + p] = col[e];
                ell_v[r * CAP + p] = val[e];
            }
        }
    } else {
        int idx = (blockIdx.x - gridE) * THREADS + threadIdx.x;
        int r = idx >> 5;
        int f = idx & 31;
        if (r >= n) return;
        const float* xr = X + (size_t)r * K;
        float acc = 0.f;
        for (int k = 0; k < K; k += 4) {
            floatx4 x = *reinterpret_cast<const floatx4*>(xr + k);
            acc = fmaf(x.x, W0[(k + 0) * 32 + f], acc);
            acc = fmaf(x.y, W0[(k + 1) * 32 + f], acc);
            acc = fmaf(x.z, W0[(k + 2) * 32 + f], acc);
            acc = fmaf(x.w, W0[(k + 3) * 32 + f], acc);
        }
        Y[r * 32 + f] = f2b(acc);
    }
}

// ---------------- fused SpMM(+relu) + 32xFOUT GEMM  (bf16 activations) ----------------

template <int FOUT>
__global__ void fused_spmm_gemm_kernel(const int* __restrict__ nxt, const int* __restrict__ ell_c,
                                       const float* __restrict__ ell_v,
                                       const unsigned short* __restrict__ Yin,
                                       const float* __restrict__ W,
                                       unsigned short* __restrict__ Yout, int n) {
    __shared__ float w[32 * FOUT];
    const int t = threadIdx.x;
    for (int i = t; i < 32 * FOUT; i += THREADS) w[i] = W[i];
    __syncthreads();

    int g = (blockIdx.x * THREADS + t) >> 5;
    if (g >= n) return;
    int f = t & 31;
    int deg = min(nxt[g], CAP);
    int base = g * CAP;
    float acc = 0.f;
    int i = 0;
    for (; i + 8 <= deg; i += 8) {
        int4    cc0 = *reinterpret_cast<const int4*>(ell_c + base + i);
        int4    cc1 = *reinterpret_cast<const int4*>(ell_c + base + i + 4);
        floatx4 vv0 = *reinterpret_cast<const floatx4*>(ell_v + base + i);
        floatx4 vv1 = *reinterpret_cast<const floatx4*>(ell_v + base + i + 4);
        float y0 = b2f(Yin[(size_t)cc0.x * 32 + f]);
        float y1 = b2f(Yin[(size_t)cc0.y * 32 + f]);
        float y2 = b2f(Yin[(size_t)cc0.z * 32 + f]);
        float y3 = b2f(Yin[(size_t)cc0.w * 32 + f]);
        float y4 = b2f(Yin[(size_t)cc1.x * 32 + f]);
        float y5 = b2f(Yin[(size_t)cc1.y * 32 + f]);
        float y6 = b2f(Yin[(size_t)cc1.z * 32 + f]);
        float y7 = b2f(Yin[(size_t)cc1.w * 32 + f]);
        acc = fmaf(vv0.x, y0, acc);
        acc = fmaf(vv0.y, y1, acc);
        acc = fmaf(vv0.z, y2, acc);
        acc = fmaf(vv0.w, y3, acc);
        acc = fmaf(vv1.x, y4, acc);
        acc = fmaf(vv1.y, y5, acc);
        acc = fmaf(vv1.z, y6, acc);
        acc = fmaf(vv1.w, y7, acc);
    }
    for (; i + 4 <= deg; i += 4) {
        int4    cc = *reinterpret_cast<const int4*>(ell_c + base + i);
        floatx4 vv = *reinterpret_cast<const floatx4*>(ell_v + base + i);
        acc = fmaf(vv.x, b2f(Yin[(size_t)cc.x * 32 + f]), acc);
        acc = fmaf(vv.y, b2f(Yin[(size_t)cc.y * 32 + f]), acc);
        acc = fmaf(vv.z, b2f(Yin[(size_t)cc.z * 32 + f]), acc);
        acc = fmaf(vv.w, b2f(Yin[(size_t)cc.w * 32 + f]), acc);
    }
    for (; i < deg; ++i)
        acc = fmaf(ell_v[base + i], b2f(Yin[(size_t)ell_c[base + i] * 32 + f]), acc);
    float h = fmaxf(acc, 0.f);

    const int fo = f & (FOUT - 1);
    float y = 0.f;
#pragma unroll
    for (int k = 0; k < 32; ++k)
        y = fmaf(__shfl(h, k, 32), w[k * FOUT + fo], y);
    if (f < FOUT) Yout[(size_t)g * FOUT + f] = f2b(y);
}

// final z = A @ Y16 (no relu); 16 lanes/row, bf16 in, fp32 out
__global__ void spmm16_kernel(const int* __restrict__ nxt, const int* __restrict__ ell_c,
                              const float* __restrict__ ell_v,
                              const unsigned short* __restrict__ Yin,
                              float* __restrict__ Z, int n) {
    int g = (blockIdx.x * blockDim.x + threadIdx.x) >> 4;
    if (g >= n) return;
    int f = threadIdx.x & 15;
    int deg = min(nxt[g], CAP);
    int base = g * CAP;
    float acc = 0.f;
    int i = 0;
    for (; i + 8 <= deg; i += 8) {
        int4    cc0 = *reinterpret_cast<const int4*>(ell_c + base + i);
        int4    cc1 = *reinterpret_cast<const int4*>(ell_c + base + i + 4);
        floatx4 vv0 = *reinterpret_cast<const floatx4*>(ell_v + base + i);
        floatx4 vv1 = *reinterpret_cast<const floatx4*>(ell_v + base + i + 4);
        acc = fmaf(vv0.x, b2f(Yin[(size_t)cc0.x * 16 + f]), acc);
        acc = fmaf(vv0.y, b2f(Yin[(size_t)cc0.y * 16 + f]), acc);
        acc = fmaf(vv0.z, b2f(Yin[(size_t)cc0.z * 16 + f]), acc);
        acc = fmaf(vv0.w, b2f(Yin[(size_t)cc0.w * 16 + f]), acc);
        acc = fmaf(vv1.x, b2f(Yin[(size_t)cc1.x * 16 + f]), acc);
        acc = fmaf(vv1.y, b2f(Yin[(size_t)cc1.y * 16 + f]), acc);
        acc = fmaf(vv1.z, b2f(Yin[(size_t)cc1.z * 16 + f]), acc);
        acc = fmaf(vv1.w, b2f(Yin[(size_t)cc1.w * 16 + f]), acc);
    }
    for (; i + 4 <= deg; i += 4) {
        int4    cc = *reinterpret_cast<const int4*>(ell_c + base + i);
        floatx4 vv = *reinterpret_cast<const floatx4*>(ell_v + base + i);
        acc = fmaf(vv.x, b2f(Yin[(size_t)cc.x * 16 + f]), acc);
        acc = fmaf(vv.y, b2f(Yin[(size_t)cc.y * 16 + f]), acc);
        acc = fmaf(vv.z, b2f(Yin[(size_t)cc.z * 16 + f]), acc);
        acc = fmaf(vv.w, b2f(Yin[(size_t)cc.w * 16 + f]), acc);
    }
    for (; i < deg; ++i)
        acc = fmaf(ell_v[base + i], b2f(Yin[(size_t)ell_c[base + i] * 16 + f]), acc);
    Z[(size_t)g * 16 + f] = acc;
}

// ---------------- z @ z^T (fp32; nt stores) ----------------

__global__ void zzt_kernel(const float* __restrict__ z, float* __restrict__ out, int n) {
    __shared__ float zi[32][16];
    const int t = threadIdx.x;
    const int bi = blockIdx.y * 32;
    for (int i = t; i < 512; i += THREADS) {
        int r = i >> 4, c = i & 15;
        zi[r][c] = (bi + r < n) ? z[(size_t)(bi + r) * 16 + c] : 0.f;
    }
    __syncthreads();
    int j0 = blockIdx.x * 1024 + t * 4;
    if (j0 >= n) return;
    float zj[4][16];
#pragma unroll
    for (int jj = 0; jj < 4; ++jj) {
#pragma unroll
        for (int k = 0; k < 16; k += 4) {
            floatx4 v = *reinterpret_cast<const floatx4*>(z + (size_t)(j0 + jj) * 16 + k);
            zj[jj][k] = v.x; zj[jj][k + 1] = v.y; zj[jj][k + 2] = v.z; zj[jj][k + 3] = v.w;
        }
    }
#pragma unroll 4
    for (int i = 0; i < 32; ++i) {
        if (bi + i >= n) break;
        floatx4 o = {0.f, 0.f, 0.f, 0.f};
#pragma unroll
        for (int k = 0; k < 16; ++k) {
            float a = zi[i][k];
            o.x = fmaf(a, zj[0][k], o.x);
            o.y = fmaf(a, zj[1][k], o.y);
            o.z = fmaf(a, zj[2][k], o.z);
            o.w = fmaf(a, zj[3][k], o.w);
        }
        __builtin_nontemporal_store(o, reinterpret_cast<floatx4*>(out + (size_t)(bi + i) * n + j0));
    }
}

// ---------------- launch ----------------

extern "C" void kernel_launch(void* const* d_in, const int* in_sizes, int n_in,
                              void* d_out, int out_size, void* d_ws, size_t ws_size,
                              hipStream_t stream) {
    const float* features = (const float*)d_in[0];
    const int*   adj_row  = (const int*)d_in[1];
    const int*   adj_col  = (const int*)d_in[2];
    const float* adj_vals = (const float*)d_in[3];
    const float* W0 = (const float*)d_in[4];
    const float* Wh[5] = {(const float*)d_in[5], (const float*)d_in[6], (const float*)d_in[7],
                          (const float*)d_in[8], (const float*)d_in[9]};
    const float* W6 = (const float*)d_in[10];

    const int E = in_sizes[1];
    const int K = in_sizes[4] / 32;   // 512
    const int N = in_sizes[0] / K;    // 10000

    char* ws = (char*)d_ws;
    size_t off = 0;
    auto alloc = [&](size_t bytes) -> void* {
        void* p = ws + off;
        off = (off + bytes + 255) & ~(size_t)255;
        return p;
    };
    int*            nxt   = (int*)alloc((size_t)N * 4);
    int*            ell_c = (int*)alloc((size_t)N * CAP * 4);
    float*          ell_v = (float*)alloc((size_t)N * CAP * 4);
    unsigned short* Ya    = (unsigned short*)alloc((size_t)N * 32 * 2);
    unsigned short* Yb    = (unsigned short*)alloc((size_t)N * 32 * 2);
    unsigned short* Y16   = (unsigned short*)alloc((size_t)N * 16 * 2);
    float*          zbuf  = (float*)alloc((size_t)N * 16 * 4);
    int*            sink  = (int*)alloc(256);

    const int gridE = (E + THREADS - 1) / THREADS;
    const int gridG = (N * 32 + THREADS - 1) / THREADS;
    const int gridRow = gridG;

    zero_kernel<<<(N + THREADS - 1) / THREADS, THREADS, 0, stream>>>(nxt, N);
    build_and_gemm0_kernel<<<gridE + gridG, THREADS, 0, stream>>>(
        adj_row, adj_col, adj_vals, nxt, ell_c, ell_v, E, features, W0, Ya, N, K, gridE);
    probe_kernel<<<gridRow, THREADS, 0, stream>>>(sink);   // probe 1

    unsigned short* yin = Ya;
    unsigned short* yout = Yb;
    for (int l = 0; l < 5; ++l) {
        fused_spmm_gemm_kernel<32><<<gridRow, THREADS, 0, stream>>>(nxt, ell_c, ell_v, yin, Wh[l], yout, N);
        probe_kernel<<<gridRow, THREADS, 0, stream>>>(sink);   // probes 2-6
        unsigned short* tmp = yin; yin = yout; yout = tmp;
    }
    fused_spmm_gemm_kernel<16><<<gridRow, THREADS, 0, stream>>>(nxt, ell_c, ell_v, yin, W6, Y16, N);
    probe_kernel<<<gridRow, THREADS, 0, stream>>>(sink);   // probe 7
    spmm16_kernel<<<(N * 16 + THREADS - 1) / THREADS, THREADS, 0, stream>>>(nxt, ell_c, ell_v, Y16, zbuf, N);
    probe_kernel<<<gridRow, THREADS, 0, stream>>>(sink);   // probe 8

    dim3 zg((N + 1023) / 1024, (N + 31) / 32);
    zzt_kernel<<<zg, THREADS, 0, stream>>>(zbuf, (float*)d_out, N);
}

// Round 16
// 249.893 us; speedup vs baseline: 1.0015x; 1.0015x over previous
//
#include <hip/hip_runtime.h>

#define THREADS 256
#define CAP 128

typedef float floatx4 __attribute__((ext_vector_type(4)));

static __device__ __forceinline__ unsigned short f2b(float x) {
    unsigned int u = __float_as_uint(x);
    u += 0x7FFFu + ((u >> 16) & 1u);
    return (unsigned short)(u >> 16);
}
static __device__ __forceinline__ float b2f(unsigned short h) {
    return __uint_as_float(((unsigned int)h) << 16);
}

// ---------------- phase 0: zero row counters ----------------

__global__ void zero_kernel(int* __restrict__ p, int n) {
    int i = blockIdx.x * blockDim.x + threadIdx.x;
    if (i < n) p[i] = 0;
}

// ---------------- phase 1 (merged): ELL scatter  ||  gemm0 ----------------

__global__ void build_and_gemm0_kernel(const int* __restrict__ row, const int* __restrict__ col,
                                       const float* __restrict__ val, int* __restrict__ nxt,
                                       int* __restrict__ ell_c, float* __restrict__ ell_v, int E,
                                       const float* __restrict__ X, const float* __restrict__ W0,
                                       unsigned short* __restrict__ Y, int n, int K, int gridE) {
    if ((int)blockIdx.x < gridE) {
        int e = blockIdx.x * THREADS + threadIdx.x;
        if (e < E) {
            int r = row[e];
            int p = atomicAdd(&nxt[r], 1);
            if (p < CAP) {
                ell_c[r * CAP + p] = col[e];
                ell_v[r * CAP + p] = val[e];
            }
        }
    } else {
        int idx = (blockIdx.x - gridE) * THREADS + threadIdx.x;
        int r = idx >> 5;
        int f = idx & 31;
        if (r >= n) return;
        const float* xr = X + (size_t)r * K;
        float acc = 0.f;
        for (int k = 0; k < K; k += 4) {
            floatx4 x = *reinterpret_cast<const floatx4*>(xr + k);
            acc = fmaf(x.x, W0[(k + 0) * 32 + f], acc);
            acc = fmaf(x.y, W0[(k + 1) * 32 + f], acc);
            acc = fmaf(x.z, W0[(k + 2) * 32 + f], acc);
            acc = fmaf(x.w, W0[(k + 3) * 32 + f], acc);
        }
        Y[r * 32 + f] = f2b(acc);
    }
}

// ---------------- fused SpMM(+relu)+GEMM, TWO rows per 32-lane group ----------------
// Co-issued 8-wide batches for both rows: 16 outstanding gathers per group in
// the main loop; two independent shfl-tails interleaved.

template <int FOUT>
__global__ void fused2_kernel(const int* __restrict__ nxt, const int* __restrict__ ell_c,
                              const float* __restrict__ ell_v,
                              const unsigned short* __restrict__ Yin,
                              const float* __restrict__ W,
                              unsigned short* __restrict__ Yout, int n) {
    __shared__ float w[32 * FOUT];
    const int t = threadIdx.x;
    for (int i = t; i < 32 * FOUT; i += THREADS) w[i] = W[i];
    __syncthreads();

    int g = (blockIdx.x * THREADS + t) >> 5;       // group id = row pair
    int rA = 2 * g, rB = 2 * g + 1;
    if (rA >= n) return;
    const int f = t & 31;
    int degA = min(nxt[rA], CAP);
    int baseA = rA * CAP;
    int degB = (rB < n) ? min(nxt[rB], CAP) : 0;
    int baseB = rB * CAP;
    float accA = 0.f, accB = 0.f;
    int iA = 0, iB = 0;

    // co-issued main loop: 16 gathers in flight per group
    while (iA + 8 <= degA && iB + 8 <= degB) {
        int4    ca0 = *reinterpret_cast<const int4*>(ell_c + baseA + iA);
        int4    ca1 = *reinterpret_cast<const int4*>(ell_c + baseA + iA + 4);
        int4    cb0 = *reinterpret_cast<const int4*>(ell_c + baseB + iB);
        int4    cb1 = *reinterpret_cast<const int4*>(ell_c + baseB + iB + 4);
        floatx4 va0 = *reinterpret_cast<const floatx4*>(ell_v + baseA + iA);
        floatx4 va1 = *reinterpret_cast<const floatx4*>(ell_v + baseA + iA + 4);
        floatx4 vb0 = *reinterpret_cast<const floatx4*>(ell_v + baseB + iB);
        floatx4 vb1 = *reinterpret_cast<const floatx4*>(ell_v + baseB + iB + 4);
        float a0 = b2f(Yin[(size_t)ca0.x * 32 + f]);
        float a1 = b2f(Yin[(size_t)ca0.y * 32 + f]);
        float a2 = b2f(Yin[(size_t)ca0.z * 32 + f]);
        float a3 = b2f(Yin[(size_t)ca0.w * 32 + f]);
        float a4 = b2f(Yin[(size_t)ca1.x * 32 + f]);
        float a5 = b2f(Yin[(size_t)ca1.y * 32 + f]);
        float a6 = b2f(Yin[(size_t)ca1.z * 32 + f]);
        float a7 = b2f(Yin[(size_t)ca1.w * 32 + f]);
        float b0 = b2f(Yin[(size_t)cb0.x * 32 + f]);
        float b1 = b2f(Yin[(size_t)cb0.y * 32 + f]);
        float b2 = b2f(Yin[(size_t)cb0.z * 32 + f]);
        float b3 = b2f(Yin[(size_t)cb0.w * 32 + f]);
        float b4 = b2f(Yin[(size_t)cb1.x * 32 + f]);
        float b5 = b2f(Yin[(size_t)cb1.y * 32 + f]);
        float b6 = b2f(Yin[(size_t)cb1.z * 32 + f]);
        float b7 = b2f(Yin[(size_t)cb1.w * 32 + f]);
        accA = fmaf(va0.x, a0, accA); accA = fmaf(va0.y, a1, accA);
        accA = fmaf(va0.z, a2, accA); accA = fmaf(va0.w, a3, accA);
        accA = fmaf(va1.x, a4, accA); accA = fmaf(va1.y, a5, accA);
        accA = fmaf(va1.z, a6, accA); accA = fmaf(va1.w, a7, accA);
        accB = fmaf(vb0.x, b0, accB); accB = fmaf(vb0.y, b1, accB);
        accB = fmaf(vb0.z, b2, accB); accB = fmaf(vb0.w, b3, accB);
        accB = fmaf(vb1.x, b4, accB); accB = fmaf(vb1.y, b5, accB);
        accB = fmaf(vb1.z, b6, accB); accB = fmaf(vb1.w, b7, accB);
        iA += 8; iB += 8;
    }
    // drain row A
    for (; iA + 4 <= degA; iA += 4) {
        int4    cc = *reinterpret_cast<const int4*>(ell_c + baseA + iA);
        floatx4 vv = *reinterpret_cast<const floatx4*>(ell_v + baseA + iA);
        accA = fmaf(vv.x, b2f(Yin[(size_t)cc.x * 32 + f]), accA);
        accA = fmaf(vv.y, b2f(Yin[(size_t)cc.y * 32 + f]), accA);
        accA = fmaf(vv.z, b2f(Yin[(size_t)cc.z * 32 + f]), accA);
        accA = fmaf(vv.w, b2f(Yin[(size_t)cc.w * 32 + f]), accA);
    }
    for (; iA < degA; ++iA)
        accA = fmaf(ell_v[baseA + iA], b2f(Yin[(size_t)ell_c[baseA + iA] * 32 + f]), accA);
    // drain row B
    for (; iB + 4 <= degB; iB += 4) {
        int4    cc = *reinterpret_cast<const int4*>(ell_c + baseB + iB);
        floatx4 vv = *reinterpret_cast<const floatx4*>(ell_v + baseB + iB);
        accB = fmaf(vv.x, b2f(Yin[(size_t)cc.x * 32 + f]), accB);
        accB = fmaf(vv.y, b2f(Yin[(size_t)cc.y * 32 + f]), accB);
        accB = fmaf(vv.z, b2f(Yin[(size_t)cc.z * 32 + f]), accB);
        accB = fmaf(vv.w, b2f(Yin[(size_t)cc.w * 32 + f]), accB);
    }
    for (; iB < degB; ++iB)
        accB = fmaf(ell_v[baseB + iB], b2f(Yin[(size_t)ell_c[baseB + iB] * 32 + f]), accB);

    float hA = fmaxf(accA, 0.f);
    float hB = fmaxf(accB, 0.f);

    const int fo = f & (FOUT - 1);
    float yA = 0.f, yB = 0.f;
#pragma unroll
    for (int k = 0; k < 32; ++k) {
        float wk = w[k * FOUT + fo];
        yA = fmaf(__shfl(hA, k, 32), wk, yA);
        yB = fmaf(__shfl(hB, k, 32), wk, yB);
    }
    if (f < FOUT) {
        Yout[(size_t)rA * FOUT + f] = f2b(yA);
        if (rB < n) Yout[(size_t)rB * FOUT + f] = f2b(yB);
    }
}

// final z = A @ Y16 (no relu); 16 lanes/row, bf16 in, fp32 out
__global__ void spmm16_kernel(const int* __restrict__ nxt, const int* __restrict__ ell_c,
                              const float* __restrict__ ell_v,
                              const unsigned short* __restrict__ Yin,
                              float* __restrict__ Z, int n) {
    int g = (blockIdx.x * blockDim.x + threadIdx.x) >> 4;
    if (g >= n) return;
    int f = threadIdx.x & 15;
    int deg = min(nxt[g], CAP);
    int base = g * CAP;
    float acc = 0.f;
    int i = 0;
    for (; i + 8 <= deg; i += 8) {
        int4    cc0 = *reinterpret_cast<const int4*>(ell_c + base + i);
        int4    cc1 = *reinterpret_cast<const int4*>(ell_c + base + i + 4);
        floatx4 vv0 = *reinterpret_cast<const floatx4*>(ell_v + base + i);
        floatx4 vv1 = *reinterpret_cast<const floatx4*>(ell_v + base + i + 4);
        acc = fmaf(vv0.x, b2f(Yin[(size_t)cc0.x * 16 + f]), acc);
        acc = fmaf(vv0.y, b2f(Yin[(size_t)cc0.y * 16 + f]), acc);
        acc = fmaf(vv0.z, b2f(Yin[(size_t)cc0.z * 16 + f]), acc);
        acc = fmaf(vv0.w, b2f(Yin[(size_t)cc0.w * 16 + f]), acc);
        acc = fmaf(vv1.x, b2f(Yin[(size_t)cc1.x * 16 + f]), acc);
        acc = fmaf(vv1.y, b2f(Yin[(size_t)cc1.y * 16 + f]), acc);
        acc = fmaf(vv1.z, b2f(Yin[(size_t)cc1.z * 16 + f]), acc);
        acc = fmaf(vv1.w, b2f(Yin[(size_t)cc1.w * 16 + f]), acc);
    }
    for (; i + 4 <= deg; i += 4) {
        int4    cc = *reinterpret_cast<const int4*>(ell_c + base + i);
        floatx4 vv = *reinterpret_cast<const floatx4*>(ell_v + base + i);
        acc = fmaf(vv.x, b2f(Yin[(size_t)cc.x * 16 + f]), acc);
        acc = fmaf(vv.y, b2f(Yin[(size_t)cc.y * 16 + f]), acc);
        acc = fmaf(vv.z, b2f(Yin[(size_t)cc.z * 16 + f]), acc);
        acc = fmaf(vv.w, b2f(Yin[(size_t)cc.w * 16 + f]), acc);
    }
    for (; i < deg; ++i)
        acc = fmaf(ell_v[base + i], b2f(Yin[(size_t)ell_c[base + i] * 16 + f]), acc);
    Z[(size_t)g * 16 + f] = acc;
}

// ---------------- z @ z^T (fp32; nt stores) ----------------

__global__ void zzt_kernel(const float* __restrict__ z, float* __restrict__ out, int n) {
    __shared__ float zi[32][16];
    const int t = threadIdx.x;
    const int bi = blockIdx.y * 32;
    for (int i = t; i < 512; i += THREADS) {
        int r = i >> 4, c = i & 15;
        zi[r][c] = (bi + r < n) ? z[(size_t)(bi + r) * 16 + c] : 0.f;
    }
    __syncthreads();
    int j0 = blockIdx.x * 1024 + t * 4;
    if (j0 >= n) return;
    float zj[4][16];
#pragma unroll
    for (int jj = 0; jj < 4; ++jj) {
#pragma unroll
        for (int k = 0; k < 16; k += 4) {
            floatx4 v = *reinterpret_cast<const floatx4*>(z + (size_t)(j0 + jj) * 16 + k);
            zj[jj][k] = v.x; zj[jj][k + 1] = v.y; zj[jj][k + 2] = v.z; zj[jj][k + 3] = v.w;
        }
    }
#pragma unroll 4
    for (int i = 0; i < 32; ++i) {
        if (bi + i >= n) break;
        floatx4 o = {0.f, 0.f, 0.f, 0.f};
#pragma unroll
        for (int k = 0; k < 16; ++k) {
            float a = zi[i][k];
            o.x = fmaf(a, zj[0][k], o.x);
            o.y = fmaf(a, zj[1][k], o.y);
            o.z = fmaf(a, zj[2][k], o.z);
            o.w = fmaf(a, zj[3][k], o.w);
        }
        __builtin_nontemporal_store(o, reinterpret_cast<floatx4*>(out + (size_t)(bi + i) * n + j0));
    }
}

// ---------------- launch ----------------

extern "C" void kernel_launch(void* const* d_in, const int* in_sizes, int n_in,
                              void* d_out, int out_size, void* d_ws, size_t ws_size,
                              hipStream_t stream) {
    const float* features = (const float*)d_in[0];
    const int*   adj_row  = (const int*)d_in[1];
    const int*   adj_col  = (const int*)d_in[2];
    const float* adj_vals = (const float*)d_in[3];
    const float* W0 = (const float*)d_in[4];
    const float* Wh[5] = {(const float*)d_in[5], (const float*)d_in[6], (const float*)d_in[7],
                          (const float*)d_in[8], (const float*)d_in[9]};
    const float* W6 = (const float*)d_in[10];

    const int E = in_sizes[1];
    const int K = in_sizes[4] / 32;   // 512
    const int N = in_sizes[0] / K;    // 10000

    char* ws = (char*)d_ws;
    size_t off = 0;
    auto alloc = [&](size_t bytes) -> void* {
        void* p = ws + off;
        off = (off + bytes + 255) & ~(size_t)255;
        return p;
    };
    int*            nxt   = (int*)alloc((size_t)N * 4);
    int*            ell_c = (int*)alloc((size_t)N * CAP * 4);
    float*          ell_v = (float*)alloc((size_t)N * CAP * 4);
    unsigned short* Ya    = (unsigned short*)alloc((size_t)N * 32 * 2);
    unsigned short* Yb    = (unsigned short*)alloc((size_t)N * 32 * 2);
    unsigned short* Y16   = (unsigned short*)alloc((size_t)N * 16 * 2);
    float*          zbuf  = (float*)alloc((size_t)N * 16 * 4);

    const int gridE = (E + THREADS - 1) / THREADS;
    const int gridG = (N * 32 + THREADS - 1) / THREADS;
    const int nPair = (N + 1) / 2;
    const int gridPair = (nPair * 32 + THREADS - 1) / THREADS;

    zero_kernel<<<(N + THREADS - 1) / THREADS, THREADS, 0, stream>>>(nxt, N);
    build_and_gemm0_kernel<<<gridE + gridG, THREADS, 0, stream>>>(
        adj_row, adj_col, adj_vals, nxt, ell_c, ell_v, E, features, W0, Ya, N, K, gridE);

    unsigned short* yin = Ya;
    unsigned short* yout = Yb;
    for (int l = 0; l < 5; ++l) {
        fused2_kernel<32><<<gridPair, THREADS, 0, stream>>>(nxt, ell_c, ell_v, yin, Wh[l], yout, N);
        unsigned short* tmp = yin; yin = yout; yout = tmp;
    }
    fused2_kernel<16><<<gridPair, THREADS, 0, stream>>>(nxt, ell_c, ell_v, yin, W6, Y16, N);
    spmm16_kernel<<<(N * 16 + THREADS - 1) / THREADS, THREADS, 0, stream>>>(nxt, ell_c, ell_v, Y16, zbuf, N);

    dim3 zg((N + 1023) / 1024, (N + 31) / 32);
    zzt_kernel<<<zg, THREADS, 0, stream>>>(zbuf, (float*)d_out, N);
}

// Round 17
// 246.917 us; speedup vs baseline: 1.0136x; 1.0121x over previous
//
#include <hip/hip_runtime.h>

#define THREADS 256
#define CAP 128

typedef float floatx4 __attribute__((ext_vector_type(4)));

static __device__ __forceinline__ unsigned short f2b(float x) {
    unsigned int u = __float_as_uint(x);
    u += 0x7FFFu + ((u >> 16) & 1u);
    return (unsigned short)(u >> 16);
}
static __device__ __forceinline__ float b2f(unsigned short h) {
    return __uint_as_float(((unsigned int)h) << 16);
}

// ---------------- phase 0 ----------------

__global__ void zero_kernel(int* __restrict__ p, int n) {
    int i = blockIdx.x * blockDim.x + threadIdx.x;
    if (i < n) p[i] = 0;
}

// ---------------- phase 1 (merged): ELL scatter || gemm0 ----------------

__global__ void build_and_gemm0_kernel(const int* __restrict__ row, const int* __restrict__ col,
                                       const float* __restrict__ val, int* __restrict__ nxt,
                                       int* __restrict__ ell_c, float* __restrict__ ell_v, int E,
                                       const float* __restrict__ X, const float* __restrict__ W0,
                                       unsigned short* __restrict__ Y, int n, int K, int gridE) {
    if ((int)blockIdx.x < gridE) {
        int e = blockIdx.x * THREADS + threadIdx.x;
        if (e < E) {
            int r = row[e];
            int p = atomicAdd(&nxt[r], 1);
            if (p < CAP) {
                ell_c[r * CAP + p] = col[e];
                ell_v[r * CAP + p] = val[e];
            }
        }
    } else {
        int idx = (blockIdx.x - gridE) * THREADS + threadIdx.x;
        int r = idx >> 5;
        int f = idx & 31;
        if (r >= n) return;
        const float* xr = X + (size_t)r * K;
        float acc = 0.f;
        for (int k = 0; k < K; k += 4) {
            floatx4 x = *reinterpret_cast<const floatx4*>(xr + k);
            acc = fmaf(x.x, W0[(k + 0) * 32 + f], acc);
            acc = fmaf(x.y, W0[(k + 1) * 32 + f], acc);
            acc = fmaf(x.z, W0[(k + 2) * 32 + f], acc);
            acc = fmaf(x.w, W0[(k + 3) * 32 + f], acc);
        }
        Y[r * 32 + f] = f2b(acc);
    }
}

// ---------------- pure SpMM + relu (bf16 in -> bf16 out), no GEMM tail ----------------

__global__ void spmm_relu_kernel(const int* __restrict__ nxt, const int* __restrict__ ell_c,
                                 const float* __restrict__ ell_v,
                                 const unsigned short* __restrict__ Yin,
                                 unsigned short* __restrict__ H, int n) {
    int g = (blockIdx.x * blockDim.x + threadIdx.x) >> 5;
    if (g >= n) return;
    int f = threadIdx.x & 31;
    int deg = min(nxt[g], CAP);
    int base = g * CAP;
    float acc = 0.f;
    int i = 0;
    for (; i + 8 <= deg; i += 8) {
        int4    cc0 = *reinterpret_cast<const int4*>(ell_c + base + i);
        int4    cc1 = *reinterpret_cast<const int4*>(ell_c + base + i + 4);
        floatx4 vv0 = *reinterpret_cast<const floatx4*>(ell_v + base + i);
        floatx4 vv1 = *reinterpret_cast<const floatx4*>(ell_v + base + i + 4);
        float y0 = b2f(Yin[(size_t)cc0.x * 32 + f]);
        float y1 = b2f(Yin[(size_t)cc0.y * 32 + f]);
        float y2 = b2f(Yin[(size_t)cc0.z * 32 + f]);
        float y3 = b2f(Yin[(size_t)cc0.w * 32 + f]);
        float y4 = b2f(Yin[(size_t)cc1.x * 32 + f]);
        float y5 = b2f(Yin[(size_t)cc1.y * 32 + f]);
        float y6 = b2f(Yin[(size_t)cc1.z * 32 + f]);
        float y7 = b2f(Yin[(size_t)cc1.w * 32 + f]);
        acc = fmaf(vv0.x, y0, acc);
        acc = fmaf(vv0.y, y1, acc);
        acc = fmaf(vv0.z, y2, acc);
        acc = fmaf(vv0.w, y3, acc);
        acc = fmaf(vv1.x, y4, acc);
        acc = fmaf(vv1.y, y5, acc);
        acc = fmaf(vv1.z, y6, acc);
        acc = fmaf(vv1.w, y7, acc);
    }
    for (; i + 4 <= deg; i += 4) {
        int4    cc = *reinterpret_cast<const int4*>(ell_c + base + i);
        floatx4 vv = *reinterpret_cast<const floatx4*>(ell_v + base + i);
        acc = fmaf(vv.x, b2f(Yin[(size_t)cc.x * 32 + f]), acc);
        acc = fmaf(vv.y, b2f(Yin[(size_t)cc.y * 32 + f]), acc);
        acc = fmaf(vv.z, b2f(Yin[(size_t)cc.z * 32 + f]), acc);
        acc = fmaf(vv.w, b2f(Yin[(size_t)cc.w * 32 + f]), acc);
    }
    for (; i < deg; ++i)
        acc = fmaf(ell_v[base + i], b2f(Yin[(size_t)ell_c[base + i] * 32 + f]), acc);
    H[(size_t)g * 32 + f] = f2b(fmaxf(acc, 0.f));
}

// ---------------- dense H[n x 32] @ W[32 x FOUT] -> Y bf16, LDS-staged, no shfl ----------------
// block = 256 threads = 8 rows x 32 lanes. H tile staged in LDS (512B); lane f
// reads lds_h[r][k] (broadcast within row-group) + w[k][f] -> no shuffles at all.

template <int FOUT>
__global__ void gemm32_kernel(const unsigned short* __restrict__ H, const float* __restrict__ W,
                              unsigned short* __restrict__ Y, int n) {
    __shared__ float w[32 * FOUT];
    __shared__ float hh[8][32];
    const int t = threadIdx.x;
    for (int i = t; i < 32 * FOUT; i += THREADS) w[i] = W[i];
    int rbase = blockIdx.x * 8;
    {
        int r = t >> 5, k = t & 31;
        int rr = rbase + r;
        hh[r][k] = (rr < n) ? b2f(H[(size_t)rr * 32 + k]) : 0.f;
    }
    __syncthreads();
    int r = t >> 5;
    int f = t & 31;
    int rr = rbase + r;
    if (rr >= n) return;
    const int fo = f & (FOUT - 1);
    float y = 0.f;
#pragma unroll
    for (int k = 0; k < 32; ++k)
        y = fmaf(hh[r][k], w[k * FOUT + fo], y);
    if (f < FOUT) Y[(size_t)rr * FOUT + fo] = f2b(y);
}

// final z = A @ Y16 (no relu); 16 lanes/row, bf16 in, fp32 out
__global__ void spmm16_kernel(const int* __restrict__ nxt, const int* __restrict__ ell_c,
                              const float* __restrict__ ell_v,
                              const unsigned short* __restrict__ Yin,
                              float* __restrict__ Z, int n) {
    int g = (blockIdx.x * blockDim.x + threadIdx.x) >> 4;
    if (g >= n) return;
    int f = threadIdx.x & 15;
    int deg = min(nxt[g], CAP);
    int base = g * CAP;
    float acc = 0.f;
    int i = 0;
    for (; i + 8 <= deg; i += 8) {
        int4    cc0 = *reinterpret_cast<const int4*>(ell_c + base + i);
        int4    cc1 = *reinterpret_cast<const int4*>(ell_c + base + i + 4);
        floatx4 vv0 = *reinterpret_cast<const floatx4*>(ell_v + base + i);
        floatx4 vv1 = *reinterpret_cast<const floatx4*>(ell_v + base + i + 4);
        acc = fmaf(vv0.x, b2f(Yin[(size_t)cc0.x * 16 + f]), acc);
        acc = fmaf(vv0.y, b2f(Yin[(size_t)cc0.y * 16 + f]), acc);
        acc = fmaf(vv0.z, b2f(Yin[(size_t)cc0.z * 16 + f]), acc);
        acc = fmaf(vv0.w, b2f(Yin[(size_t)cc0.w * 16 + f]), acc);
        acc = fmaf(vv1.x, b2f(Yin[(size_t)cc1.x * 16 + f]), acc);
        acc = fmaf(vv1.y, b2f(Yin[(size_t)cc1.y * 16 + f]), acc);
        acc = fmaf(vv1.z, b2f(Yin[(size_t)cc1.z * 16 + f]), acc);
        acc = fmaf(vv1.w, b2f(Yin[(size_t)cc1.w * 16 + f]), acc);
    }
    for (; i + 4 <= deg; i += 4) {
        int4    cc = *reinterpret_cast<const int4*>(ell_c + base + i);
        floatx4 vv = *reinterpret_cast<const floatx4*>(ell_v + base + i);
        acc = fmaf(vv.x, b2f(Yin[(size_t)cc.x * 16 + f]), acc);
        acc = fmaf(vv.y, b2f(Yin[(size_t)cc.y * 16 + f]), acc);
        acc = fmaf(vv.z, b2f(Yin[(size_t)cc.z * 16 + f]), acc);
        acc = fmaf(vv.w, b2f(Yin[(size_t)cc.w * 16 + f]), acc);
    }
    for (; i < deg; ++i)
        acc = fmaf(ell_v[base + i], b2f(Yin[(size_t)ell_c[base + i] * 16 + f]), acc);
    Z[(size_t)g * 16 + f] = acc;
}

// ---------------- z @ z^T (fp32; nt stores) ----------------

__global__ void zzt_kernel(const float* __restrict__ z, float* __restrict__ out, int n) {
    __shared__ float zi[32][16];
    const int t = threadIdx.x;
    const int bi = blockIdx.y * 32;
    for (int i = t; i < 512; i += THREADS) {
        int r = i >> 4, c = i & 15;
        zi[r][c] = (bi + r < n) ? z[(size_t)(bi + r) * 16 + c] : 0.f;
    }
    __syncthreads();
    int j0 = blockIdx.x * 1024 + t * 4;
    if (j0 >= n) return;
    float zj[4][16];
#pragma unroll
    for (int jj = 0; jj < 4; ++jj) {
#pragma unroll
        for (int k = 0; k < 16; k += 4) {
            floatx4 v = *reinterpret_cast<const floatx4*>(z + (size_t)(j0 + jj) * 16 + k);
            zj[jj][k] = v.x; zj[jj][k + 1] = v.y; zj[jj][k + 2] = v.z; zj[jj][k + 3] = v.w;
        }
    }
#pragma unroll 4
    for (int i = 0; i < 32; ++i) {
        if (bi + i >= n) break;
        floatx4 o = {0.f, 0.f, 0.f, 0.f};
#pragma unroll
        for (int k = 0; k < 16; ++k) {
            float a = zi[i][k];
            o.x = fmaf(a, zj[0][k], o.x);
            o.y = fmaf(a, zj[1][k], o.y);
            o.z = fmaf(a, zj[2][k], o.z);
            o.w = fmaf(a, zj[3][k], o.w);
        }
        __builtin_nontemporal_store(o, reinterpret_cast<floatx4*>(out + (size_t)(bi + i) * n + j0));
    }
}

// ---------------- launch ----------------

extern "C" void kernel_launch(void* const* d_in, const int* in_sizes, int n_in,
                              void* d_out, int out_size, void* d_ws, size_t ws_size,
                              hipStream_t stream) {
    const float* features = (const float*)d_in[0];
    const int*   adj_row  = (const int*)d_in[1];
    const int*   adj_col  = (const int*)d_in[2];
    const float* adj_vals = (const float*)d_in[3];
    const float* W0 = (const float*)d_in[4];
    const float* Wh[5] = {(const float*)d_in[5], (const float*)d_in[6], (const float*)d_in[7],
                          (const float*)d_in[8], (const float*)d_in[9]};
    const float* W6 = (const float*)d_in[10];

    const int E = in_sizes[1];
    const int K = in_sizes[4] / 32;   // 512
    const int N = in_sizes[0] / K;    // 10000

    char* ws = (char*)d_ws;
    size_t off = 0;
    auto alloc = [&](size_t bytes) -> void* {
        void* p = ws + off;
        off = (off + bytes + 255) & ~(size_t)255;
        return p;
    };
    int*            nxt   = (int*)alloc((size_t)N * 4);
    int*            ell_c = (int*)alloc((size_t)N * CAP * 4);
    float*          ell_v = (float*)alloc((size_t)N * CAP * 4);
    unsigned short* Ya    = (unsigned short*)alloc((size_t)N * 32 * 2);
    unsigned short* Yb    = (unsigned short*)alloc((size_t)N * 32 * 2);
    unsigned short* Hbuf  = (unsigned short*)alloc((size_t)N * 32 * 2);
    unsigned short* Y16   = (unsigned short*)alloc((size_t)N * 16 * 2);
    float*          zbuf  = (float*)alloc((size_t)N * 16 * 4);

    const int gridE = (E + THREADS - 1) / THREADS;
    const int gridG = (N * 32 + THREADS - 1) / THREADS;
    const int gridRow = gridG;
    const int gridGemm = (N + 7) / 8;

    zero_kernel<<<(N + THREADS - 1) / THREADS, THREADS, 0, stream>>>(nxt, N);
    build_and_gemm0_kernel<<<gridE + gridG, THREADS, 0, stream>>>(
        adj_row, adj_col, adj_vals, nxt, ell_c, ell_v, E, features, W0, Ya, N, K, gridE);

    unsigned short* yin = Ya;
    unsigned short* yout = Yb;
    for (int l = 0; l < 5; ++l) {
        spmm_relu_kernel<<<gridRow, THREADS, 0, stream>>>(nxt, ell_c, ell_v, yin, Hbuf, N);
        gemm32_kernel<32><<<gridGemm, THREADS, 0, stream>>>(Hbuf, Wh[l], yout, N);
        unsigned short* tmp = yin; yin = yout; yout = tmp;
    }
    spmm_relu_kernel<<<gridRow, THREADS, 0, stream>>>(nxt, ell_c, ell_v, yin, Hbuf, N);
    gemm32_kernel<16><<<gridGemm, THREADS, 0, stream>>>(Hbuf, W6, Y16, N);
    spmm16_kernel<<<(N * 16 + THREADS - 1) / THREADS, THREADS, 0, stream>>>(nxt, ell_c, ell_v, Y16, zbuf, N);

    dim3 zg((N + 1023) / 1024, (N + 31) / 32);
    zzt_kernel<<<zg, THREADS, 0, stream>>>(zbuf, (float*)d_out, N);
}

// Round 18
// 239.696 us; speedup vs baseline: 1.0441x; 1.0301x over previous
//
#include <hip/hip_runtime.h>

#define THREADS 256
#define CAP 128

typedef float floatx4 __attribute__((ext_vector_type(4)));

static __device__ __forceinline__ unsigned short f2b(float x) {
    unsigned int u = __float_as_uint(x);
    u += 0x7FFFu + ((u >> 16) & 1u);
    return (unsigned short)(u >> 16);
}
static __device__ __forceinline__ float b2f(unsigned short h) {
    return __uint_as_float(((unsigned int)h) << 16);
}

// ---------------- phase 0 ----------------

__global__ void zero_kernel(int* __restrict__ p, int n) {
    int i = blockIdx.x * blockDim.x + threadIdx.x;
    if (i < n) p[i] = 0;
}

// ---------------- phase 1 (merged): ELL scatter || gemm0 ----------------

__global__ void build_and_gemm0_kernel(const int* __restrict__ row, const int* __restrict__ col,
                                       const float* __restrict__ val, int* __restrict__ nxt,
                                       int* __restrict__ ell_c, float* __restrict__ ell_v, int E,
                                       const float* __restrict__ X, const float* __restrict__ W0,
                                       unsigned short* __restrict__ Y, int n, int K, int gridE) {
    if ((int)blockIdx.x < gridE) {
        int e = blockIdx.x * THREADS + threadIdx.x;
        if (e < E) {
            int r = row[e];
            int p = atomicAdd(&nxt[r], 1);
            if (p < CAP) {
                ell_c[r * CAP + p] = col[e];
                ell_v[r * CAP + p] = val[e];
            }
        }
    } else {
        int idx = (blockIdx.x - gridE) * THREADS + threadIdx.x;
        int r = idx >> 5;
        int f = idx & 31;
        if (r >= n) return;
        const float* xr = X + (size_t)r * K;
        float acc = 0.f;
        for (int k = 0; k < K; k += 4) {
            floatx4 x = *reinterpret_cast<const floatx4*>(xr + k);
            acc = fmaf(x.x, W0[(k + 0) * 32 + f], acc);
            acc = fmaf(x.y, W0[(k + 1) * 32 + f], acc);
            acc = fmaf(x.z, W0[(k + 2) * 32 + f], acc);
            acc = fmaf(x.w, W0[(k + 3) * 32 + f], acc);
        }
        Y[r * 32 + f] = f2b(acc);
    }
}

// ---------------- fused SpMM(+relu) + 32xFOUT GEMM  (bf16, 16-wide gathers) ----------------

template <int FOUT>
__global__ void fused_spmm_gemm_kernel(const int* __restrict__ nxt, const int* __restrict__ ell_c,
                                       const float* __restrict__ ell_v,
                                       const unsigned short* __restrict__ Yin,
                                       const float* __restrict__ W,
                                       unsigned short* __restrict__ Yout, int n) {
    __shared__ float w[32 * FOUT];
    const int t = threadIdx.x;
    for (int i = t; i < 32 * FOUT; i += THREADS) w[i] = W[i];
    __syncthreads();

    int g = (blockIdx.x * THREADS + t) >> 5;
    if (g >= n) return;
    int f = t & 31;
    int deg = min(nxt[g], CAP);
    int base = g * CAP;
    float acc = 0.f;
    int i = 0;
    // 16-wide: 16 independent gathers in flight per iteration
    for (; i + 16 <= deg; i += 16) {
        int4    cc0 = *reinterpret_cast<const int4*>(ell_c + base + i);
        int4    cc1 = *reinterpret_cast<const int4*>(ell_c + base + i + 4);
        int4    cc2 = *reinterpret_cast<const int4*>(ell_c + base + i + 8);
        int4    cc3 = *reinterpret_cast<const int4*>(ell_c + base + i + 12);
        floatx4 vv0 = *reinterpret_cast<const floatx4*>(ell_v + base + i);
        floatx4 vv1 = *reinterpret_cast<const floatx4*>(ell_v + base + i + 4);
        floatx4 vv2 = *reinterpret_cast<const floatx4*>(ell_v + base + i + 8);
        floatx4 vv3 = *reinterpret_cast<const floatx4*>(ell_v + base + i + 12);
        float y0  = b2f(Yin[(size_t)cc0.x * 32 + f]);
        float y1  = b2f(Yin[(size_t)cc0.y * 32 + f]);
        float y2  = b2f(Yin[(size_t)cc0.z * 32 + f]);
        float y3  = b2f(Yin[(size_t)cc0.w * 32 + f]);
        float y4  = b2f(Yin[(size_t)cc1.x * 32 + f]);
        float y5  = b2f(Yin[(size_t)cc1.y * 32 + f]);
        float y6  = b2f(Yin[(size_t)cc1.z * 32 + f]);
        float y7  = b2f(Yin[(size_t)cc1.w * 32 + f]);
        float y8  = b2f(Yin[(size_t)cc2.x * 32 + f]);
        float y9  = b2f(Yin[(size_t)cc2.y * 32 + f]);
        float y10 = b2f(Yin[(size_t)cc2.z * 32 + f]);
        float y11 = b2f(Yin[(size_t)cc2.w * 32 + f]);
        float y12 = b2f(Yin[(size_t)cc3.x * 32 + f]);
        float y13 = b2f(Yin[(size_t)cc3.y * 32 + f]);
        float y14 = b2f(Yin[(size_t)cc3.z * 32 + f]);
        float y15 = b2f(Yin[(size_t)cc3.w * 32 + f]);
        acc = fmaf(vv0.x, y0,  acc); acc = fmaf(vv0.y, y1,  acc);
        acc = fmaf(vv0.z, y2,  acc); acc = fmaf(vv0.w, y3,  acc);
        acc = fmaf(vv1.x, y4,  acc); acc = fmaf(vv1.y, y5,  acc);
        acc = fmaf(vv1.z, y6,  acc); acc = fmaf(vv1.w, y7,  acc);
        acc = fmaf(vv2.x, y8,  acc); acc = fmaf(vv2.y, y9,  acc);
        acc = fmaf(vv2.z, y10, acc); acc = fmaf(vv2.w, y11, acc);
        acc = fmaf(vv3.x, y12, acc); acc = fmaf(vv3.y, y13, acc);
        acc = fmaf(vv3.z, y14, acc); acc = fmaf(vv3.w, y15, acc);
    }
    for (; i + 8 <= deg; i += 8) {
        int4    cc0 = *reinterpret_cast<const int4*>(ell_c + base + i);
        int4    cc1 = *reinterpret_cast<const int4*>(ell_c + base + i + 4);
        floatx4 vv0 = *reinterpret_cast<const floatx4*>(ell_v + base + i);
        floatx4 vv1 = *reinterpret_cast<const floatx4*>(ell_v + base + i + 4);
        float y0 = b2f(Yin[(size_t)cc0.x * 32 + f]);
        float y1 = b2f(Yin[(size_t)cc0.y * 32 + f]);
        float y2 = b2f(Yin[(size_t)cc0.z * 32 + f]);
        float y3 = b2f(Yin[(size_t)cc0.w * 32 + f]);
        float y4 = b2f(Yin[(size_t)cc1.x * 32 + f]);
        float y5 = b2f(Yin[(size_t)cc1.y * 32 + f]);
        float y6 = b2f(Yin[(size_t)cc1.z * 32 + f]);
        float y7 = b2f(Yin[(size_t)cc1.w * 32 + f]);
        acc = fmaf(vv0.x, y0, acc); acc = fmaf(vv0.y, y1, acc);
        acc = fmaf(vv0.z, y2, acc); acc = fmaf(vv0.w, y3, acc);
        acc = fmaf(vv1.x, y4, acc); acc = fmaf(vv1.y, y5, acc);
        acc = fmaf(vv1.z, y6, acc); acc = fmaf(vv1.w, y7, acc);
    }
    for (; i + 4 <= deg; i += 4) {
        int4    cc = *reinterpret_cast<const int4*>(ell_c + base + i);
        floatx4 vv = *reinterpret_cast<const floatx4*>(ell_v + base + i);
        acc = fmaf(vv.x, b2f(Yin[(size_t)cc.x * 32 + f]), acc);
        acc = fmaf(vv.y, b2f(Yin[(size_t)cc.y * 32 + f]), acc);
        acc = fmaf(vv.z, b2f(Yin[(size_t)cc.z * 32 + f]), acc);
        acc = fmaf(vv.w, b2f(Yin[(size_t)cc.w * 32 + f]), acc);
    }
    for (; i < deg; ++i)
        acc = fmaf(ell_v[base + i], b2f(Yin[(size_t)ell_c[base + i] * 32 + f]), acc);
    float h = fmaxf(acc, 0.f);

    const int fo = f & (FOUT - 1);
    float y = 0.f;
#pragma unroll
    for (int k = 0; k < 32; ++k)
        y = fmaf(__shfl(h, k, 32), w[k * FOUT + fo], y);
    if (f < FOUT) Yout[(size_t)g * FOUT + f] = f2b(y);
}

// final z = A @ Y16 (no relu); 16 lanes/row, bf16 in, fp32 out
__global__ void spmm16_kernel(const int* __restrict__ nxt, const int* __restrict__ ell_c,
                              const float* __restrict__ ell_v,
                              const unsigned short* __restrict__ Yin,
                              float* __restrict__ Z, int n) {
    int g = (blockIdx.x * blockDim.x + threadIdx.x) >> 4;
    if (g >= n) return;
    int f = threadIdx.x & 15;
    int deg = min(nxt[g], CAP);
    int base = g * CAP;
    float acc = 0.f;
    int i = 0;
    for (; i + 8 <= deg; i += 8) {
        int4    cc0 = *reinterpret_cast<const int4*>(ell_c + base + i);
        int4    cc1 = *reinterpret_cast<const int4*>(ell_c + base + i + 4);
        floatx4 vv0 = *reinterpret_cast<const floatx4*>(ell_v + base + i);
        floatx4 vv1 = *reinterpret_cast<const floatx4*>(ell_v + base + i + 4);
        acc = fmaf(vv0.x, b2f(Yin[(size_t)cc0.x * 16 + f]), acc);
        acc = fmaf(vv0.y, b2f(Yin[(size_t)cc0.y * 16 + f]), acc);
        acc = fmaf(vv0.z, b2f(Yin[(size_t)cc0.z * 16 + f]), acc);
        acc = fmaf(vv0.w, b2f(Yin[(size_t)cc0.w * 16 + f]), acc);
        acc = fmaf(vv1.x, b2f(Yin[(size_t)cc1.x * 16 + f]), acc);
        acc = fmaf(vv1.y, b2f(Yin[(size_t)cc1.y * 16 + f]), acc);
        acc = fmaf(vv1.z, b2f(Yin[(size_t)cc1.z * 16 + f]), acc);
        acc = fmaf(vv1.w, b2f(Yin[(size_t)cc1.w * 16 + f]), acc);
    }
    for (; i + 4 <= deg; i += 4) {
        int4    cc = *reinterpret_cast<const int4*>(ell_c + base + i);
        floatx4 vv = *reinterpret_cast<const floatx4*>(ell_v + base + i);
        acc = fmaf(vv.x, b2f(Yin[(size_t)cc.x * 16 + f]), acc);
        acc = fmaf(vv.y, b2f(Yin[(size_t)cc.y * 16 + f]), acc);
        acc = fmaf(vv.z, b2f(Yin[(size_t)cc.z * 16 + f]), acc);
        acc = fmaf(vv.w, b2f(Yin[(size_t)cc.w * 16 + f]), acc);
    }
    for (; i < deg; ++i)
        acc = fmaf(ell_v[base + i], b2f(Yin[(size_t)ell_c[base + i] * 16 + f]), acc);
    Z[(size_t)g * 16 + f] = acc;
}

// ---------------- z @ z^T (fp32; nt stores) ----------------

__global__ void zzt_kernel(const float* __restrict__ z, float* __restrict__ out, int n) {
    __shared__ float zi[32][16];
    const int t = threadIdx.x;
    const int bi = blockIdx.y * 32;
    for (int i = t; i < 512; i += THREADS) {
        int r = i >> 4, c = i & 15;
        zi[r][c] = (bi + r < n) ? z[(size_t)(bi + r) * 16 + c] : 0.f;
    }
    __syncthreads();
    int j0 = blockIdx.x * 1024 + t * 4;
    if (j0 >= n) return;
    float zj[4][16];
#pragma unroll
    for (int jj = 0; jj < 4; ++jj) {
#pragma unroll
        for (int k = 0; k < 16; k += 4) {
            floatx4 v = *reinterpret_cast<const floatx4*>(z + (size_t)(j0 + jj) * 16 + k);
            zj[jj][k] = v.x; zj[jj][k + 1] = v.y; zj[jj][k + 2] = v.z; zj[jj][k + 3] = v.w;
        }
    }
#pragma unroll 4
    for (int i = 0; i < 32; ++i) {
        if (bi + i >= n) break;
        floatx4 o = {0.f, 0.f, 0.f, 0.f};
#pragma unroll
        for (int k = 0; k < 16; ++k) {
            float a = zi[i][k];
            o.x = fmaf(a, zj[0][k], o.x);
            o.y = fmaf(a, zj[1][k], o.y);
            o.z = fmaf(a, zj[2][k], o.z);
            o.w = fmaf(a, zj[3][k], o.w);
        }
        __builtin_nontemporal_store(o, reinterpret_cast<floatx4*>(out + (size_t)(bi + i) * n + j0));
    }
}

// ---------------- launch ----------------

extern "C" void kernel_launch(void* const* d_in, const int* in_sizes, int n_in,
                              void* d_out, int out_size, void* d_ws, size_t ws_size,
                              hipStream_t stream) {
    const float* features = (const float*)d_in[0];
    const int*   adj_row  = (const int*)d_in[1];
    const int*   adj_col  = (const int*)d_in[2];
    const float* adj_vals = (const float*)d_in[3];
    const float* W0 = (const float*)d_in[4];
    const float* Wh[5] = {(const float*)d_in[5], (const float*)d_in[6], (const float*)d_in[7],
                          (const float*)d_in[8], (const float*)d_in[9]};
    const float* W6 = (const float*)d_in[10];

    const int E = in_sizes[1];
    const int K = in_sizes[4] / 32;   // 512
    const int N = in_sizes[0] / K;    // 10000

    char* ws = (char*)d_ws;
    size_t off = 0;
    auto alloc = [&](size_t bytes) -> void* {
        void* p = ws + off;
        off = (off + bytes + 255) & ~(size_t)255;
        return p;
    };
    int*            nxt   = (int*)alloc((size_t)N * 4);
    int*            ell_c = (int*)alloc((size_t)N * CAP * 4);
    float*          ell_v = (float*)alloc((size_t)N * CAP * 4);
    unsigned short* Ya    = (unsigned short*)alloc((size_t)N * 32 * 2);
    unsigned short* Yb    = (unsigned short*)alloc((size_t)N * 32 * 2);
    unsigned short* Y16   = (unsigned short*)alloc((size_t)N * 16 * 2);
    float*          zbuf  = (float*)alloc((size_t)N * 16 * 4);

    const int gridE = (E + THREADS - 1) / THREADS;
    const int gridG = (N * 32 + THREADS - 1) / THREADS;
    const int gridRow = gridG;

    zero_kernel<<<(N + THREADS - 1) / THREADS, THREADS, 0, stream>>>(nxt, N);
    build_and_gemm0_kernel<<<gridE + gridG, THREADS, 0, stream>>>(
        adj_row, adj_col, adj_vals, nxt, ell_c, ell_v, E, features, W0, Ya, N, K, gridE);

    unsigned short* yin = Ya;
    unsigned short* yout = Yb;
    for (int l = 0; l < 5; ++l) {
        fused_spmm_gemm_kernel<32><<<gridRow, THREADS, 0, stream>>>(nxt, ell_c, ell_v, yin, Wh[l], yout, N);
        unsigned short* tmp = yin; yin = yout; yout = tmp;
    }
    fused_spmm_gemm_kernel<16><<<gridRow, THREADS, 0, stream>>>(nxt, ell_c, ell_v, yin, W6, Y16, N);
    spmm16_kernel<<<(N * 16 + THREADS - 1) / THREADS, THREADS, 0, stream>>>(nxt, ell_c, ell_v, Y16, zbuf, N);

    dim3 zg((N + 1023) / 1024, (N + 31) / 32);
    zzt_kernel<<<zg, THREADS, 0, stream>>>(zbuf, (float*)d_out, N);
}

// Round 19
// 236.763 us; speedup vs baseline: 1.0571x; 1.0124x over previous
//
#include <hip/hip_runtime.h>

#define THREADS 256
#define CAP 128

typedef float floatx4 __attribute__((ext_vector_type(4)));

static __device__ __forceinline__ unsigned short f2b(float x) {
    unsigned int u = __float_as_uint(x);
    u += 0x7FFFu + ((u >> 16) & 1u);
    return (unsigned short)(u >> 16);
}
static __device__ __forceinline__ float b2f(unsigned short h) {
    return __uint_as_float(((unsigned int)h) << 16);
}
static __device__ __forceinline__ float b2f_lo(unsigned int u) {
    return __uint_as_float(u << 16);
}
static __device__ __forceinline__ float b2f_hi(unsigned int u) {
    return __uint_as_float(u & 0xFFFF0000u);
}

// ---------------- phase 0 ----------------

__global__ void zero_kernel(int* __restrict__ p, int n) {
    int i = blockIdx.x * blockDim.x + threadIdx.x;
    if (i < n) p[i] = 0;
}

// ---------------- phase 1 (merged): ELL scatter || gemm0 ----------------

__global__ void build_and_gemm0_kernel(const int* __restrict__ row, const int* __restrict__ col,
                                       const float* __restrict__ val, int* __restrict__ nxt,
                                       int* __restrict__ ell_c, float* __restrict__ ell_v, int E,
                                       const float* __restrict__ X, const float* __restrict__ W0,
                                       unsigned short* __restrict__ Y, int n, int K, int gridE) {
    if ((int)blockIdx.x < gridE) {
        int e = blockIdx.x * THREADS + threadIdx.x;
        if (e < E) {
            int r = row[e];
            int p = atomicAdd(&nxt[r], 1);
            if (p < CAP) {
                ell_c[r * CAP + p] = col[e];
                ell_v[r * CAP + p] = val[e];
            }
        }
    } else {
        int idx = (blockIdx.x - gridE) * THREADS + threadIdx.x;
        int r = idx >> 5;
        int f = idx & 31;
        if (r >= n) return;
        const float* xr = X + (size_t)r * K;
        float acc = 0.f;
        for (int k = 0; k < K; k += 4) {
            floatx4 x = *reinterpret_cast<const floatx4*>(xr + k);
            acc = fmaf(x.x, W0[(k + 0) * 32 + f], acc);
            acc = fmaf(x.y, W0[(k + 1) * 32 + f], acc);
            acc = fmaf(x.z, W0[(k + 2) * 32 + f], acc);
            acc = fmaf(x.w, W0[(k + 3) * 32 + f], acc);
        }
        Y[r * 32 + f] = f2b(acc);
    }
}

// ---------------- fused SpMM(+relu)+GEMM, paired-feature gathers ----------------
// Lane l: feature-pair m = l&15 (features 2m,2m+1 as one uint), edge-half
// hi = l>>4. One gather instruction covers TWO edges (16 lanes per row each).
// Gather instruction count and lane-address count halve vs per-feature loads.

template <int FOUT>
__global__ void fused_pair_kernel(const int* __restrict__ nxt, const int* __restrict__ ell_c,
                                  const float* __restrict__ ell_v,
                                  const unsigned short* __restrict__ Yin,
                                  const float* __restrict__ W,
                                  unsigned short* __restrict__ Yout, int n) {
    __shared__ float w[32 * FOUT];
    const int t = threadIdx.x;
    for (int i = t; i < 32 * FOUT; i += THREADS) w[i] = W[i];
    __syncthreads();

    int g = (blockIdx.x * THREADS + t) >> 5;
    if (g >= n) return;
    const int l = t & 31;
    const int m = l & 15;
    const int hi = (l >> 4) & 1;
    int deg = min(nxt[g], CAP);
    int base = g * CAP;
    float accx = 0.f, accy = 0.f;
    int i = 0;
    for (; i + 16 <= deg; i += 16) {
        int4    cc0 = *reinterpret_cast<const int4*>(ell_c + base + i);
        int4    cc1 = *reinterpret_cast<const int4*>(ell_c + base + i + 4);
        int4    cc2 = *reinterpret_cast<const int4*>(ell_c + base + i + 8);
        int4    cc3 = *reinterpret_cast<const int4*>(ell_c + base + i + 12);
        floatx4 vv0 = *reinterpret_cast<const floatx4*>(ell_v + base + i);
        floatx4 vv1 = *reinterpret_cast<const floatx4*>(ell_v + base + i + 4);
        floatx4 vv2 = *reinterpret_cast<const floatx4*>(ell_v + base + i + 8);
        floatx4 vv3 = *reinterpret_cast<const floatx4*>(ell_v + base + i + 12);
        int c0 = hi ? cc0.y : cc0.x;
        int c1 = hi ? cc0.w : cc0.z;
        int c2 = hi ? cc1.y : cc1.x;
        int c3 = hi ? cc1.w : cc1.z;
        int c4 = hi ? cc2.y : cc2.x;
        int c5 = hi ? cc2.w : cc2.z;
        int c6 = hi ? cc3.y : cc3.x;
        int c7 = hi ? cc3.w : cc3.z;
        unsigned int u0 = *reinterpret_cast<const unsigned int*>(Yin + (((size_t)c0) << 5) + (m << 1));
        unsigned int u1 = *reinterpret_cast<const unsigned int*>(Yin + (((size_t)c1) << 5) + (m << 1));
        unsigned int u2 = *reinterpret_cast<const unsigned int*>(Yin + (((size_t)c2) << 5) + (m << 1));
        unsigned int u3 = *reinterpret_cast<const unsigned int*>(Yin + (((size_t)c3) << 5) + (m << 1));
        unsigned int u4 = *reinterpret_cast<const unsigned int*>(Yin + (((size_t)c4) << 5) + (m << 1));
        unsigned int u5 = *reinterpret_cast<const unsigned int*>(Yin + (((size_t)c5) << 5) + (m << 1));
        unsigned int u6 = *reinterpret_cast<const unsigned int*>(Yin + (((size_t)c6) << 5) + (m << 1));
        unsigned int u7 = *reinterpret_cast<const unsigned int*>(Yin + (((size_t)c7) << 5) + (m << 1));
        float v0 = hi ? vv0.y : vv0.x;
        float v1 = hi ? vv0.w : vv0.z;
        float v2 = hi ? vv1.y : vv1.x;
        float v3 = hi ? vv1.w : vv1.z;
        float v4 = hi ? vv2.y : vv2.x;
        float v5 = hi ? vv2.w : vv2.z;
        float v6 = hi ? vv3.y : vv3.x;
        float v7 = hi ? vv3.w : vv3.z;
        accx = fmaf(v0, b2f_lo(u0), accx); accy = fmaf(v0, b2f_hi(u0), accy);
        accx = fmaf(v1, b2f_lo(u1), accx); accy = fmaf(v1, b2f_hi(u1), accy);
        accx = fmaf(v2, b2f_lo(u2), accx); accy = fmaf(v2, b2f_hi(u2), accy);
        accx = fmaf(v3, b2f_lo(u3), accx); accy = fmaf(v3, b2f_hi(u3), accy);
        accx = fmaf(v4, b2f_lo(u4), accx); accy = fmaf(v4, b2f_hi(u4), accy);
        accx = fmaf(v5, b2f_lo(u5), accx); accy = fmaf(v5, b2f_hi(u5), accy);
        accx = fmaf(v6, b2f_lo(u6), accx); accy = fmaf(v6, b2f_hi(u6), accy);
        accx = fmaf(v7, b2f_lo(u7), accx); accy = fmaf(v7, b2f_hi(u7), accy);
    }
    for (; i + 2 <= deg; i += 2) {
        int c = ell_c[base + i + hi];
        float v = ell_v[base + i + hi];
        unsigned int u = *reinterpret_cast<const unsigned int*>(Yin + (((size_t)c) << 5) + (m << 1));
        accx = fmaf(v, b2f_lo(u), accx);
        accy = fmaf(v, b2f_hi(u), accy);
    }
    if (i < deg && !hi) {
        int c = ell_c[base + i];
        float v = ell_v[base + i];
        unsigned int u = *reinterpret_cast<const unsigned int*>(Yin + (((size_t)c) << 5) + (m << 1));
        accx = fmaf(v, b2f_lo(u), accx);
        accy = fmaf(v, b2f_hi(u), accy);
    }
    accx += __shfl_xor(accx, 16);
    accy += __shfl_xor(accy, 16);
    float hx = fmaxf(accx, 0.f);   // feature 2m
    float hy = fmaxf(accy, 0.f);   // feature 2m+1

    const int fo = l & (FOUT - 1);
    float y = 0.f;
#pragma unroll
    for (int j = 0; j < 16; ++j) {
        y = fmaf(__shfl(hx, j, 32), w[(2 * j) * FOUT + fo], y);
        y = fmaf(__shfl(hy, j, 32), w[(2 * j + 1) * FOUT + fo], y);
    }
    if (l < FOUT) Yout[(size_t)g * FOUT + l] = f2b(y);
}

// final z = A @ Y16 (no relu); 16 lanes/row, bf16 in, fp32 out
__global__ void spmm16_kernel(const int* __restrict__ nxt, const int* __restrict__ ell_c,
                              const float* __restrict__ ell_v,
                              const unsigned short* __restrict__ Yin,
                              float* __restrict__ Z, int n) {
    int g = (blockIdx.x * blockDim.x + threadIdx.x) >> 4;
    if (g >= n) return;
    int f = threadIdx.x & 15;
    int deg = min(nxt[g], CAP);
    int base = g * CAP;
    float acc = 0.f;
    int i = 0;
    for (; i + 8 <= deg; i += 8) {
        int4    cc0 = *reinterpret_cast<const int4*>(ell_c + base + i);
        int4    cc1 = *reinterpret_cast<const int4*>(ell_c + base + i + 4);
        floatx4 vv0 = *reinterpret_cast<const floatx4*>(ell_v + base + i);
        floatx4 vv1 = *reinterpret_cast<const floatx4*>(ell_v + base + i + 4);
        acc = fmaf(vv0.x, b2f(Yin[(size_t)cc0.x * 16 + f]), acc);
        acc = fmaf(vv0.y, b2f(Yin[(size_t)cc0.y * 16 + f]), acc);
        acc = fmaf(vv0.z, b2f(Yin[(size_t)cc0.z * 16 + f]), acc);
        acc = fmaf(vv0.w, b2f(Yin[(size_t)cc0.w * 16 + f]), acc);
        acc = fmaf(vv1.x, b2f(Yin[(size_t)cc1.x * 16 + f]), acc);
        acc = fmaf(vv1.y, b2f(Yin[(size_t)cc1.y * 16 + f]), acc);
        acc = fmaf(vv1.z, b2f(Yin[(size_t)cc1.z * 16 + f]), acc);
        acc = fmaf(vv1.w, b2f(Yin[(size_t)cc1.w * 16 + f]), acc);
    }
    for (; i + 4 <= deg; i += 4) {
        int4    cc = *reinterpret_cast<const int4*>(ell_c + base + i);
        floatx4 vv = *reinterpret_cast<const floatx4*>(ell_v + base + i);
        acc = fmaf(vv.x, b2f(Yin[(size_t)cc.x * 16 + f]), acc);
        acc = fmaf(vv.y, b2f(Yin[(size_t)cc.y * 16 + f]), acc);
        acc = fmaf(vv.z, b2f(Yin[(size_t)cc.z * 16 + f]), acc);
        acc = fmaf(vv.w, b2f(Yin[(size_t)cc.w * 16 + f]), acc);
    }
    for (; i < deg; ++i)
        acc = fmaf(ell_v[base + i], b2f(Yin[(size_t)ell_c[base + i] * 16 + f]), acc);
    Z[(size_t)g * 16 + f] = acc;
}

// ---------------- z @ z^T (fp32; nt stores) ----------------

__global__ void zzt_kernel(const float* __restrict__ z, float* __restrict__ out, int n) {
    __shared__ float zi[32][16];
    const int t = threadIdx.x;
    const int bi = blockIdx.y * 32;
    for (int i = t; i < 512; i += THREADS) {
        int r = i >> 4, c = i & 15;
        zi[r][c] = (bi + r < n) ? z[(size_t)(bi + r) * 16 + c] : 0.f;
    }
    __syncthreads();
    int j0 = blockIdx.x * 1024 + t * 4;
    if (j0 >= n) return;
    float zj[4][16];
#pragma unroll
    for (int jj = 0; jj < 4; ++jj) {
#pragma unroll
        for (int k = 0; k < 16; k += 4) {
            floatx4 v = *reinterpret_cast<const floatx4*>(z + (size_t)(j0 + jj) * 16 + k);
            zj[jj][k] = v.x; zj[jj][k + 1] = v.y; zj[jj][k + 2] = v.z; zj[jj][k + 3] = v.w;
        }
    }
#pragma unroll 4
    for (int i = 0; i < 32; ++i) {
        if (bi + i >= n) break;
        floatx4 o = {0.f, 0.f, 0.f, 0.f};
#pragma unroll
        for (int k = 0; k < 16; ++k) {
            float a = zi[i][k];
            o.x = fmaf(a, zj[0][k], o.x);
            o.y = fmaf(a, zj[1][k], o.y);
            o.z = fmaf(a, zj[2][k], o.z);
            o.w = fmaf(a, zj[3][k], o.w);
        }
        __builtin_nontemporal_store(o, reinterpret_cast<floatx4*>(out + (size_t)(bi + i) * n + j0));
    }
}

// ---------------- launch ----------------

extern "C" void kernel_launch(void* const* d_in, const int* in_sizes, int n_in,
                              void* d_out, int out_size, void* d_ws, size_t ws_size,
                              hipStream_t stream) {
    const float* features = (const float*)d_in[0];
    const int*   adj_row  = (const int*)d_in[1];
    const int*   adj_col  = (const int*)d_in[2];
    const float* adj_vals = (const float*)d_in[3];
    const float* W0 = (const float*)d_in[4];
    const float* Wh[5] = {(const float*)d_in[5], (const float*)d_in[6], (const float*)d_in[7],
                          (const float*)d_in[8], (const float*)d_in[9]};
    const float* W6 = (const float*)d_in[10];

    const int E = in_sizes[1];
    const int K = in_sizes[4] / 32;   // 512
    const int N = in_sizes[0] / K;    // 10000

    char* ws = (char*)d_ws;
    size_t off = 0;
    auto alloc = [&](size_t bytes) -> void* {
        void* p = ws + off;
        off = (off + bytes + 255) & ~(size_t)255;
        return p;
    };
    int*            nxt   = (int*)alloc((size_t)N * 4);
    int*            ell_c = (int*)alloc((size_t)N * CAP * 4);
    float*          ell_v = (float*)alloc((size_t)N * CAP * 4);
    unsigned short* Ya    = (unsigned short*)alloc((size_t)N * 32 * 2);
    unsigned short* Yb    = (unsigned short*)alloc((size_t)N * 32 * 2);
    unsigned short* Y16   = (unsigned short*)alloc((size_t)N * 16 * 2);
    float*          zbuf  = (float*)alloc((size_t)N * 16 * 4);

    const int gridE = (E + THREADS - 1) / THREADS;
    const int gridG = (N * 32 + THREADS - 1) / THREADS;
    const int gridRow = gridG;

    zero_kernel<<<(N + THREADS - 1) / THREADS, THREADS, 0, stream>>>(nxt, N);
    build_and_gemm0_kernel<<<gridE + gridG, THREADS, 0, stream>>>(
        adj_row, adj_col, adj_vals, nxt, ell_c, ell_v, E, features, W0, Ya, N, K, gridE);

    unsigned short* yin = Ya;
    unsigned short* yout = Yb;
    for (int l = 0; l < 5; ++l) {
        fused_pair_kernel<32><<<gridRow, THREADS, 0, stream>>>(nxt, ell_c, ell_v, yin, Wh[l], yout, N);
        unsigned short* tmp = yin; yin = yout; yout = tmp;
    }
    fused_pair_kernel<16><<<gridRow, THREADS, 0, stream>>>(nxt, ell_c, ell_v, yin, W6, Y16, N);
    spmm16_kernel<<<(N * 16 + THREADS - 1) / THREADS, THREADS, 0, stream>>>(nxt, ell_c, ell_v, Y16, zbuf, N);

    dim3 zg((N + 1023) / 1024, (N + 31) / 32);
    zzt_kernel<<<zg, THREADS, 0, stream>>>(zbuf, (float*)d_out, N);
}